// Round 11
// baseline (388.794 us; speedup 1.0000x reference)
//
#include <hip/hip_runtime.h>

// Problem constants
#define NB    32
#define CDIM  256
#define HWSZ  4096                 // 64*64
#define NPOS  (NB*HWSZ)            // 131072
#define KCODES 1024
#define QELEMS ((size_t)NB*CDIM*HWSZ)   // 33554432
#define IDX_OFF QELEMS
#define DIFF_OFF (QELEMS + NPOS)
// Codebook: 48 regions x 32 KB = 1.5 MB in d_out scratch.
// Region r<16: eh k-chunk r | 16..31: (el*64) chunk r-16 | 32..47: (eh/64) chunk r-32
#define EBYTES (48*32768)
#define E2F_OFF (EBYTES/4)         // float offset 393216 for e2 table

// LDS map (stage1): A 96 KB (xh | xh/64 | xl*64) + scratch
#define X2P   98304                // x2 partials [16][64] f32 = 4 KB
#define X2T   102400               // x2 totals  [64] f32
#define MVOFF 102656               // merge vals [16][64] f32 = 4 KB
#define MIOFF 106752               // merge idx  [16][64] i32 = 4 KB
#define LDSSZ 110848

typedef _Float16       f16x8  __attribute__((ext_vector_type(8)));
typedef float          f32x16 __attribute__((ext_vector_type(16)));
typedef unsigned short u16x8  __attribute__((ext_vector_type(8)));

static __device__ inline unsigned short f2h(float f) {
    _Float16 h = (_Float16)f;
    return __builtin_bit_cast(unsigned short, h);
}

// ---------------------------------------------------------------------------
// prep_embed: codebook rearranged + pre-scaled for stage1 register loads.
// Within region: byte = code*32 + kh*16 + sub*2   (kh=(c>>3)&1, sub=c&7).
// Also e2[k] (fp32); zero diff accumulator.
// ---------------------------------------------------------------------------
__global__ __launch_bounds__(64) void vq_prep_embed(const float* __restrict__ embed,
                                                    float* __restrict__ out) {
    const int k = blockIdx.x;
    const int lane = threadIdx.x;
    const float4 v = *reinterpret_cast<const float4*>(embed + (size_t)k * CDIM + lane * 4);

    unsigned char* __restrict__ ebuf = (unsigned char*)out;

    _Float16 h0 = (_Float16)v.x, h1 = (_Float16)v.y, h2 = (_Float16)v.z, h3 = (_Float16)v.w;
    ushort4 hv = { __builtin_bit_cast(unsigned short, h0), __builtin_bit_cast(unsigned short, h1),
                   __builtin_bit_cast(unsigned short, h2), __builtin_bit_cast(unsigned short, h3) };
    ushort4 lv = { f2h((v.x - (float)h0) * 64.0f), f2h((v.y - (float)h1) * 64.0f),
                   f2h((v.z - (float)h2) * 64.0f), f2h((v.w - (float)h3) * 64.0f) };
    ushort4 hv64 = { f2h((float)h0 * 0.015625f), f2h((float)h1 * 0.015625f),
                     f2h((float)h2 * 0.015625f), f2h((float)h3 * 0.015625f) };

    const int c0  = lane * 4;
    const int kc  = c0 >> 4;             // k-chunk 0..15
    const int kh  = (c0 >> 3) & 1;
    const int sub = c0 & 7;
    const size_t byte = (size_t)kc * 32768 + (size_t)k * 32 + kh * 16 + sub * 2;
    *reinterpret_cast<ushort4*>(ebuf + byte)              = hv;    // eh    (regions 0-15)
    *reinterpret_cast<ushort4*>(ebuf + byte + 16 * 32768) = lv;    // el*64 (regions 16-31)
    *reinterpret_cast<ushort4*>(ebuf + byte + 32 * 32768) = hv64;  // eh/64 (regions 32-47)

    float s = v.x * v.x + v.y * v.y + v.z * v.z + v.w * v.w;
    #pragma unroll
    for (int m = 1; m < 64; m <<= 1) s += __shfl_xor(s, m, 64);
    if (lane == 0) out[E2F_OFF + k] = s;
    if (k == 0 && lane == 0) out[DIFF_OFF] = 0.0f;
}

// ---------------------------------------------------------------------------
// stage1: fused fp16-split 32x32x16 MFMA distance + argmin + diff.
// 1024 thr = 16 waves; wave w covers all 64 positions x codes [w*64, w*64+64).
// acc[2][2] = 64 AGPR; B pipelined 3-deep in registers (pair for step k loads
// a full unrolled iteration before use -> L2 latency covered in-wave).
// Virtual K = 768 as 48 steps: seg0 xh*eh | seg1 (xh/64)*(el*64) |
// seg2 (xl*64)*(eh/64) — all scales pre-baked, zero VALU in loop.
// A from LDS (read-only after prologue). NO barriers in the K-loop.
// ---------------------------------------------------------------------------
__global__ __launch_bounds__(1024) void vq_stage1(const float* __restrict__ x,
                                                  float* __restrict__ out) {
    __shared__ __align__(16) unsigned char lds[LDSSZ];

    const unsigned char* __restrict__ ebuf = (const unsigned char*)out;
    const float* __restrict__ e2buf = out + E2F_OFF;
    float* __restrict__ idx_out = out + IDX_OFF;

    const int t     = threadIdx.x;
    const int lane  = t & 63;
    const int col32 = lane & 31;
    const int hi    = lane >> 5;
    const int widx  = t >> 6;          // wave 0..15 : code group of 64

    const int pos0 = blockIdx.x * 64;
    const int n    = pos0 >> 12;
    const int hw0  = pos0 & 4095;
    const float* __restrict__ xbase = x + (size_t)n * (CDIM * HWSZ) + hw0;

    // ---- A staging: x fp32 -> fp16 {xh, xh/64, xl*64}, [16 kc][2 kh][64 pos][16B]
    {
        const int i = t & 63;          // position (coalesced)
        const int g = t >> 6;          // channel group 0..15 (16 ch each)
        float x2p = 0.f;
        #pragma unroll
        for (int j = 0; j < 2; ++j) {
            const int c0 = g * 16 + j * 8;
            u16x8 hv, lv, hv64;
            #pragma unroll
            for (int q = 0; q < 8; ++q) {
                float vv = xbase[(size_t)(c0 + q) * HWSZ + i];
                x2p = fmaf(vv, vv, x2p);
                _Float16 hh = (_Float16)vv;
                hv[q]   = __builtin_bit_cast(unsigned short, hh);
                lv[q]   = f2h((vv - (float)hh) * 64.0f);
                hv64[q] = f2h((float)hh * 0.015625f);
            }
            const int byte = g * 2048 + j * 1024 + i * 16;   // kc=g, kh=j
            *reinterpret_cast<u16x8*>(lds + byte)         = hv;    // xh
            *reinterpret_cast<u16x8*>(lds + byte + 32768) = hv64;  // xh/64
            *reinterpret_cast<u16x8*>(lds + byte + 65536) = lv;    // xl*64
        }
        ((float*)(lds + X2P))[g * 64 + i] = x2p;
    }
    __syncthreads();

    // x2 totals
    if (t < 64) {
        const float* p = (const float*)(lds + X2P);
        float s = 0.f;
        #pragma unroll
        for (int g = 0; g < 16; ++g) s += p[g * 64 + t];
        ((float*)(lds + X2T))[t] = s;
    }
    __syncthreads();

    f32x16 acc00 = {}, acc01 = {}, acc10 = {}, acc11 = {};

    const int aoff = hi * 1024 + col32 * 16;   // + ra*512 ; + region*32768 + kc*2048
    const unsigned char* __restrict__ bl =
        ebuf + (size_t)((widx * 64 + col32) * 32 + hi * 16);   // + kq*32768 + cb*1024

    auto bload = [&](int kq, int cb) {
        return *reinterpret_cast<const f16x8*>(bl + (size_t)kq * 32768 + cb * 1024);
    };
    auto aload = [&](int kq, int ra) {
        // A region = kq>>4 (seg), chunk = kq&15
        return *reinterpret_cast<const f16x8*>(
            lds + (kq >> 4) * 32768 + (kq & 15) * 2048 + aoff + ra * 512);
    };

    // ---- main loop: 48 steps, 3-deep named B pipeline, period 3 x unroll 6.
    // Pair for step k is loaded one full unrolled-2 iteration before use.
    f16x8 bA0 = bload(0, 0), bA1 = bload(0, 1);     // pair kq
    f16x8 bB0 = bload(1, 0), bB1 = bload(1, 1);     // pair kq+1
    f16x8 bC0, bC1;                                  // landing slot

    // STEP2(cur, nxt, spare, kq): consumes cur(kq), nxt(kq+1);
    // loads kq+2 into spare, kq+3 into cur's regs.
#define STEP2(cA0, cA1, cB0, cB1, cC0, cC1, KQ)                                   \
    {                                                                             \
        cC0 = bload((KQ) + 2, 0); cC1 = bload((KQ) + 2, 1);                       \
        f16x8 a0 = aload((KQ), 0), a1 = aload((KQ), 1);                           \
        __builtin_amdgcn_s_setprio(1);                                            \
        acc00 = __builtin_amdgcn_mfma_f32_32x32x16_f16(a0, cA0, acc00, 0, 0, 0);  \
        acc01 = __builtin_amdgcn_mfma_f32_32x32x16_f16(a0, cA1, acc01, 0, 0, 0);  \
        acc10 = __builtin_amdgcn_mfma_f32_32x32x16_f16(a1, cA0, acc10, 0, 0, 0);  \
        acc11 = __builtin_amdgcn_mfma_f32_32x32x16_f16(a1, cA1, acc11, 0, 0, 0);  \
        __builtin_amdgcn_s_setprio(0);                                            \
        cA0 = bload((KQ) + 3, 0); cA1 = bload((KQ) + 3, 1);                       \
        f16x8 a0n = aload((KQ) + 1, 0), a1n = aload((KQ) + 1, 1);                 \
        __builtin_amdgcn_s_setprio(1);                                            \
        acc00 = __builtin_amdgcn_mfma_f32_32x32x16_f16(a0n, cB0, acc00, 0, 0, 0); \
        acc01 = __builtin_amdgcn_mfma_f32_32x32x16_f16(a0n, cB1, acc01, 0, 0, 0); \
        acc10 = __builtin_amdgcn_mfma_f32_32x32x16_f16(a1n, cB0, acc10, 0, 0, 0); \
        acc11 = __builtin_amdgcn_mfma_f32_32x32x16_f16(a1n, cB1, acc11, 0, 0, 0); \
        __builtin_amdgcn_s_setprio(0);                                            \
    }

    for (int kq = 0; kq < 48; kq += 6) {
        STEP2(bA0, bA1, bB0, bB1, bC0, bC1, kq);         // after: bC=kq+2, bA=kq+3
        STEP2(bC0, bC1, bA0, bA1, bB0, bB1, kq + 2);     // after: bB=kq+4, bC=kq+5
        STEP2(bB0, bB1, bC0, bC1, bA0, bA1, kq + 4);     // after: bA=kq+6, bB=kq+7
    }
#undef STEP2

    // ---- epilogue: scores, in-wave argmin, cross-wave merge
    const float* x2t = (const float*)(lds + X2T);
    const float e2v0 = e2buf[widx * 64 + col32];
    const float e2v1 = e2buf[widx * 64 + 32 + col32];

    float* mv = (float*)(lds + MVOFF);
    int*   mi = (int*)(lds + MIOFF);

    #pragma unroll
    for (int ra = 0; ra < 2; ++ra) {
        #pragma unroll
        for (int reg = 0; reg < 16; ++reg) {
            const int pos = ra * 32 + (reg & 3) + 8 * (reg >> 2) + 4 * hi;
            const float x2 = x2t[pos];
            const float d0 = (ra == 0) ? acc00[reg] : acc10[reg];
            const float d1 = (ra == 0) ? acc01[reg] : acc11[reg];
            float bv_ = (x2 - 2.0f * d0) + e2v0;
            int   bi_ = widx * 64 + col32;
            const float s1 = (x2 - 2.0f * d1) + e2v1;
            const int   c1 = widx * 64 + 32 + col32;
            if (s1 < bv_) { bv_ = s1; bi_ = c1; }
            // shuffle-merge over the 32 code columns (stays within 32-lane half)
            #pragma unroll
            for (int m = 1; m < 32; m <<= 1) {
                float ov = __shfl_xor(bv_, m, 64);
                int   oi = __shfl_xor(bi_, m, 64);
                if (ov < bv_ || (ov == bv_ && oi < bi_)) { bv_ = ov; bi_ = oi; }
            }
            if (col32 == 0) {
                mv[widx * 64 + pos] = bv_;
                mi[widx * 64 + pos] = bi_;
            }
        }
    }

    __syncthreads();
    if (t < 64) {
        float bv_ = mv[t];
        int   bi_ = mi[t];
        #pragma unroll
        for (int w = 1; w < 16; ++w) {
            const float ov = mv[w * 64 + t];
            const int   oi = mi[w * 64 + t];
            if (ov < bv_ || (ov == bv_ && oi < bi_)) { bv_ = ov; bi_ = oi; }
        }
        idx_out[pos0 + t] = (float)bi_;
        // diff partial = sum of min distances
        float d = bv_;
        #pragma unroll
        for (int m = 1; m < 64; m <<= 1) d += __shfl_xor(d, m, 64);
        if (t == 0) atomicAdd(out + DIFF_OFF, d * (1.0f / 33554432.0f));
    }
}

// ---------------------------------------------------------------------------
// gather: quantize = embed[idx] (NCHW). Diff already done in stage1.
// ---------------------------------------------------------------------------
__global__ __launch_bounds__(256) void vq_gather_kernel(const float* __restrict__ embed,
                                                        float* __restrict__ out) {
    const int tid = threadIdx.x;
    const int p = blockIdx.x * 256 + tid;
    const int n = p >> 12;
    const int hw = p & 4095;
    const int idx = (int)out[IDX_OFF + p];
    const float4* __restrict__ erow4 = reinterpret_cast<const float4*>(embed + (size_t)idx * CDIM);
    float* __restrict__ op = out + (size_t)n * (CDIM * HWSZ) + hw;

    #pragma unroll 8
    for (int c4 = 0; c4 < 64; ++c4) {
        const float4 e = erow4[c4];
        op[(size_t)(c4 * 4 + 0) * HWSZ] = e.x;
        op[(size_t)(c4 * 4 + 1) * HWSZ] = e.y;
        op[(size_t)(c4 * 4 + 2) * HWSZ] = e.z;
        op[(size_t)(c4 * 4 + 3) * HWSZ] = e.w;
    }
}

extern "C" void kernel_launch(void* const* d_in, const int* in_sizes, int n_in,
                              void* d_out, int out_size, void* d_ws, size_t ws_size,
                              hipStream_t stream) {
    const float* x = (const float*)d_in[0];
    const float* embed = (const float*)d_in[1];
    float* out = (float*)d_out;

    vq_prep_embed<<<KCODES, 64, 0, stream>>>(embed, out);
    vq_stage1<<<NPOS / 64, 1024, 0, stream>>>(x, out);
    vq_gather_kernel<<<NPOS / 256, 256, 0, stream>>>(embed, out);
}